// Round 8
// baseline (222.169 us; speedup 1.0000x reference)
//
#include <hip/hip_runtime.h>
#include <math.h>

// Problem constants (B=8, T=4096, D=256, K=1024)
#define NTOK   32768
#define NDIM   256
#define NCODE  1024
#define CHUNK  4096           // f16 per (strip,kc8) chunk: 128 codes x 32 dims = 8 KB

typedef _Float16 f16x8 __attribute__((ext_vector_type(8)));
typedef float    f32x4 __attribute__((ext_vector_type(4)));

// ---------------------------------------------------------------------------
// Prep: split codebook (fp32) into f16 hi/lo planes, blocked k-major layout.
//   chunk = (strip = row/128, kc8 = dim/32); within chunk:
//   off_f16 = (r>>4)*512 + (g&3)*128 + (r&15)*8     (r = row%128, g&3 = k-quad)
// One MFMA B-fragment tile (16 codes x 32 dims) is a contiguous 1 KB region
// -> a wave's 16B/lane global load of it is perfectly coalesced.
// Plus exact fp32 row norms. ~1 MB total (L2-resident everywhere).
// ---------------------------------------------------------------------------
__global__ __launch_bounds__(256) void prep_cb(
        const float* __restrict__ cb,
        _Float16* __restrict__ ch, _Float16* __restrict__ cl,
        float* __restrict__ csq) {
    const int L   = blockIdx.x * 256 + threadIdx.x;   // 0..32767
    const int row = L >> 5;                           // code 0..1023
    const int g   = L & 31;                           // 8-elem group in 256 dims

    const float* src = cb + (size_t)row * NDIM + g * 8;
    float4 a0 = *(const float4*)src;
    float4 a1 = *(const float4*)(src + 4);
    float v[8] = {a0.x, a0.y, a0.z, a0.w, a1.x, a1.y, a1.z, a1.w};
    f16x8 hi, lo;
    float s = 0.f;
    #pragma unroll
    for (int e = 0; e < 8; ++e) {
        _Float16 h = (_Float16)v[e];
        hi[e] = h;
        lo[e] = (_Float16)(v[e] - (float)h);
        s += v[e] * v[e];
    }
    const int r = row & 127;
    const size_t dst = (size_t)((row >> 7) * 8 + (g >> 2)) * CHUNK
                     + (r >> 4) * 512 + (g & 3) * 128 + (r & 15) * 8;
    *(f16x8*)&ch[dst] = hi;
    *(f16x8*)&cl[dst] = lo;
    #pragma unroll
    for (int off = 16; off > 0; off >>= 1) s += __shfl_down(s, off, 32);
    if ((threadIdx.x & 31) == 0) csq[row] = s;
}

// ---------------------------------------------------------------------------
// Main: A-in-LDS fused VQ. Campaign constraints (rounds 0-7, all measured):
//   - MFMA floor 26us (fixed); TA floor = 16cyc x B-dwordx4-count -> need
//     >=3 MFMA per B-load => 32 rows/wave (r7: 16 rows => 54us TA floor).
//   - Overlapping the two floors needs 4 waves/SIMD (r0-r5: five schemes at
//     2 waves/SIMD all tie at ~65us, latency-serialized).
//   - 4 waves/SIMD => <=128 VGPR; A-in-registers alone is 128 => A must
//     live in LDS (read per chunk, 4 ds_read_b128, contiguous 1KB frags).
// Block = 512 thr / 8 waves / 64 tokens; wave = (my in 2) x (nx in 4):
// 32 rows x 2 column-tiles, full K. Per chunk per wave: 4 ds_read (A) +
// 4 dwordx4 (B, global->reg from L2-resident planes) + 12 MFMA; pairwise
// register double-buffer (prefetch chunk c+1 while MFMA chunk c). Live regs
// ~110 <= 128, pinned via __launch_bounds__(512, 4) (r6/r7 lesson: unpinned
// allocator chose 64 and spilled/starved). LDS 64KB + overlapped scratch ->
// 2 blocks/CU = 16 waves/CU = 4/SIMD. No main-loop barriers (A-LDS is
// read-only after one sync); my-partner waves share B addresses (L1 reuse).
// 3-pass f16 MFMA (ah.bh + al.bh + ah.bl); per-lane running argmin;
// acc zeroed via zero-C on each strip's first chunk.
// Layouts (verified): A/B frag [row=lane&15][k=(lane>>4)*8+j]; D col=lane&15,
// row=(lane>>4)*4+reg.
// ---------------------------------------------------------------------------

// Load A frags (kc8 = CN) + B frags (global chunk GCN) into a register set.
#define PRE(CN, GCN, AH, AL, BH, BL) do {                                    \
    AH[0] = *(const f16x8*)&A_lds[my2    ][CN][0][aoff];                     \
    AL[0] = *(const f16x8*)&A_lds[my2    ][CN][1][aoff];                     \
    AH[1] = *(const f16x8*)&A_lds[my2 + 1][CN][0][aoff];                     \
    AL[1] = *(const f16x8*)&A_lds[my2 + 1][CN][1][aoff];                     \
    const _Float16* _ph = pbh + (size_t)(GCN) * CHUNK;                       \
    const _Float16* _pl = pbl + (size_t)(GCN) * CHUNK;                       \
    BH[0] = *(const f16x8*)&_ph[0];                                          \
    BH[1] = *(const f16x8*)&_ph[512];                                        \
    BL[0] = *(const f16x8*)&_pl[0];                                          \
    BL[1] = *(const f16x8*)&_pl[512];                                        \
} while (0)

// One step: prefetch next set, then 12 MFMA on the current set.
#define STEP(CN, GCN, CAH, CAL, CBH, CBL, NAH, NAL, NBH, NBL, FIRSTZ, DOPREF) \
do {                                                                         \
    if (DOPREF) PRE(CN, GCN, NAH, NAL, NBH, NBL);                            \
    __builtin_amdgcn_s_setprio(1);                                           \
    _Pragma("unroll")                                                        \
    for (int _mt = 0; _mt < 2; ++_mt)                                        \
        _Pragma("unroll")                                                    \
        for (int _t = 0; _t < 2; ++_t) {                                     \
            acc[_mt][_t] = __builtin_amdgcn_mfma_f32_16x16x32_f16(           \
                CAH[_mt], CBH[_t], (FIRSTZ) ? zz : acc[_mt][_t], 0, 0, 0);   \
            acc[_mt][_t] = __builtin_amdgcn_mfma_f32_16x16x32_f16(           \
                CAL[_mt], CBH[_t], acc[_mt][_t], 0, 0, 0);                   \
            acc[_mt][_t] = __builtin_amdgcn_mfma_f32_16x16x32_f16(           \
                CAH[_mt], CBL[_t], acc[_mt][_t], 0, 0, 0);                   \
        }                                                                    \
    __builtin_amdgcn_s_setprio(0);                                           \
} while (0)

__global__ __launch_bounds__(512, 4) void vq_main(
        const float* __restrict__ z,
        const _Float16* __restrict__ ch, const _Float16* __restrict__ cl,
        const float* __restrict__ csq, const float* __restrict__ cb,
        float* __restrict__ zq, float* __restrict__ io) {
    // A planes in frag layout: [rowblock16][kc8][hi/lo][1KB frag] = 64 KB.
    // Reused as epilogue scratch after the main loop (guarded by syncs).
    __shared__ _Float16 A_lds[4][8][2][512];

    const int tid  = threadIdx.x;
    const int w    = tid >> 6;                 // 0..7
    const int lane = tid & 63;
    const int quad = lane >> 4, lr = lane & 15;
    const int my   = w >> 2;                   // 0..1 token half (32 rows)
    const int nx   = w & 3;                    // 0..3 column quarter (2 tiles)
    const int my2  = my * 2;
    const int m0   = blockIdx.x * 64;

    // ---- prologue: convert z rows of this block into A_lds (hi/lo) ----
    // item = (row 0..63, g 0..31): read 8 f32, split, write two 16B frags.
    #pragma unroll
    for (int i = 0; i < 4; ++i) {
        const int item = tid + i * 512;        // 0..2047
        const int row  = item >> 5;
        const int g    = item & 31;
        const float* src = z + (size_t)(m0 + row) * NDIM + g * 8;
        float4 a0 = *(const float4*)src;
        float4 a1 = *(const float4*)(src + 4);
        float v[8] = {a0.x, a0.y, a0.z, a0.w, a1.x, a1.y, a1.z, a1.w};
        f16x8 hi, lo;
        #pragma unroll
        for (int e = 0; e < 8; ++e) {
            _Float16 h = (_Float16)v[e];
            hi[e] = h;
            lo[e] = (_Float16)(v[e] - (float)h);
        }
        _Float16* dst = &A_lds[row >> 4][g >> 2][0][(g & 3) * 128 + (row & 15) * 8];
        *(f16x8*)dst = hi;
        *(f16x8*)(dst + 512) = lo;             // plane stride = 512 f16
    }
    __syncthreads();

    // per-lane offsets/bases
    const int aoff = quad * 128 + lr * 8;                       // within 1KB frag
    const _Float16* pbh = ch + (nx * 2) * 512 + aoff;           // B tile pair base
    const _Float16* pbl = cl + (nx * 2) * 512 + aoff;

    float bv[2][4];
    int   bi[2][4];
    #pragma unroll
    for (int mt = 0; mt < 2; ++mt)
        #pragma unroll
        for (int r = 0; r < 4; ++r) { bv[mt][r] = INFINITY; bi[mt][r] = 0x7fffffff; }

    const f32x4 zz = (f32x4){0.f, 0.f, 0.f, 0.f};
    f32x4 acc[2][2];

    // register sets (pairwise double buffer)
    f16x8 a0h[2], a0l[2], b0h[2], b0l[2];
    f16x8 a1h[2], a1l[2], b1h[2], b1l[2];

    PRE(0, 0, a0h, a0l, b0h, b0l);             // chunk 0 -> set 0

    for (int s = 0; s < 8; ++s) {
        const int gb = s * 8;
        const int lp = (s < 7);                // strip 7: no prefetch past end
        STEP(1, gb + 1, a0h, a0l, b0h, b0l, a1h, a1l, b1h, b1l, 1, 1);
        STEP(2, gb + 2, a1h, a1l, b1h, b1l, a0h, a0l, b0h, b0l, 0, 1);
        STEP(3, gb + 3, a0h, a0l, b0h, b0l, a1h, a1l, b1h, b1l, 0, 1);
        STEP(4, gb + 4, a1h, a1l, b1h, b1l, a0h, a0l, b0h, b0l, 0, 1);
        STEP(5, gb + 5, a0h, a0l, b0h, b0l, a1h, a1l, b1h, b1l, 0, 1);
        STEP(6, gb + 6, a1h, a1l, b1h, b1l, a0h, a0l, b0h, b0l, 0, 1);
        STEP(7, gb + 7, a0h, a0l, b0h, b0l, a1h, a1l, b1h, b1l, 0, 1);
        STEP(0, gb + 8, a1h, a1l, b1h, b1l, a0h, a0l, b0h, b0l, 0, lp);

        // ---- fold strip s into the running per-lane argmin ----
        #pragma unroll
        for (int mt = 0; mt < 2; ++mt)
            #pragma unroll
            for (int t = 0; t < 2; ++t) {
                const int   n  = s * 128 + (nx * 2 + t) * 16 + lr;
                const float cs = csq[n];
                #pragma unroll
                for (int r = 0; r < 4; ++r) {
                    float v = cs - 2.0f * acc[mt][t][r];
                    if (v < bv[mt][r] || (v == bv[mt][r] && n < bi[mt][r])) {
                        bv[mt][r] = v; bi[mt][r] = n;
                    }
                }
            }
    }

    // ---- butterfly over the 16 lanes sharing each row ----
    #pragma unroll
    for (int msk = 1; msk < 16; msk <<= 1)
        #pragma unroll
        for (int mt = 0; mt < 2; ++mt)
            #pragma unroll
            for (int r = 0; r < 4; ++r) {
                float ov = __shfl_xor(bv[mt][r], msk, 64);
                int   oi = __shfl_xor(bi[mt][r], msk, 64);
                if (ov < bv[mt][r] || (ov == bv[mt][r] && oi < bi[mt][r])) {
                    bv[mt][r] = ov; bi[mt][r] = oi;
                }
            }

    __syncthreads();                           // all A_lds reads done; reuse
    float* sval  = (float*)&A_lds[0][0][0][0]; // [64][4]
    int*   sidx  = (int*)(sval + 256);         // [64][4]
    int*   bestS = (int*)(sval + 512);         // [64]

    if (lr == 0) {
        #pragma unroll
        for (int mt = 0; mt < 2; ++mt)
            #pragma unroll
            for (int r = 0; r < 4; ++r) {
                int row = my * 32 + mt * 16 + quad * 4 + r;   // 0..63
                sval[row * 4 + nx] = bv[mt][r];
                sidx[row * 4 + nx] = bi[mt][r];
            }
    }
    __syncthreads();

    if (tid < 64) {
        float bvv = sval[tid * 4];
        int   bii = sidx[tid * 4];
        #pragma unroll
        for (int k = 1; k < 4; ++k) {
            float v = sval[tid * 4 + k];
            int   i = sidx[tid * 4 + k];
            if (v < bvv || (v == bvv && i < bii)) { bvv = v; bii = i; }
        }
        bestS[tid] = bii;
        io[m0 + tid] = (float)bii;
    }
    __syncthreads();

    // ---- gather z_q: 64 rows x 1 KB from cb (L2-hot), coalesced float4 ----
    const int gr = tid >> 3, gc = tid & 7;     // 64 rows x 8 threads
    const float* src = cb + (size_t)bestS[gr] * NDIM;
    float*       dst = zq + (size_t)(m0 + gr) * NDIM;
    #pragma unroll
    for (int q = 0; q < 8; ++q) {
        int col = q * 32 + gc * 4;
        *(float4*)&dst[col] = *(const float4*)&src[col];
    }
}

// ---------------------------------------------------------------------------
extern "C" void kernel_launch(void* const* d_in, const int* in_sizes, int n_in,
                              void* d_out, int out_size, void* d_ws, size_t ws_size,
                              hipStream_t stream) {
    const float* z  = (const float*)d_in[0];
    const float* cb = (const float*)d_in[1];

    float* zq = (float*)d_out;                        // 32768*256 floats
    float* io = (float*)d_out + (size_t)NTOK * NDIM;  // 32768 floats (indices)

    _Float16* ch  = (_Float16*)d_ws;                  // 0.5 MB
    _Float16* cl  = ch + (size_t)NCODE * NDIM;        // 0.5 MB
    float*    csq = (float*)(cl + (size_t)NCODE * NDIM);  // 4 KB

    prep_cb<<<NCODE * 32 / 256, 256, 0, stream>>>(cb, ch, cl, csq);

    vq_main<<<NTOK / 64, 512, 0, stream>>>(z, ch, cl, csq, cb, zq, io);
}